// Round 4
// baseline (299.181 us; speedup 1.0000x reference)
//
#include <hip/hip_runtime.h>
#include <math.h>

// ContextualLoss 3D: N=8, C=128, L=4096.
// R4: occupancy push — 4-way m-split (grid 1024 = 4 blocks-worth per CU of work),
//     __launch_bounds__(256,3) + register diet (e2 derived from b2) to fit 3 waves/SIMD,
//     two-stage vectorized k_mu (was 52us on half the CUs with scalar loads).
// Pipeline: mu1 -> mu2 -> prep -> rowmax -> post1 -> z -> post2 -> colmax -> loss.

#define NB 8
#define CC 128
#define LL 4096
#define CL (CC * LL)
#define EPSV 1e-5f
#define L2E 1.44269504f
#define TWO_L2E 2.88539008f

typedef __bf16 bf16x8 __attribute__((ext_vector_type(8)));
typedef float f32x4 __attribute__((ext_vector_type(4)));

// f32 -> bf16 bits, round-nearest-even
__device__ __forceinline__ unsigned short f2bf(float f) {
    unsigned u = __float_as_uint(f);
    u += 0x7FFFu + ((u >> 16) & 1u);
    return (unsigned short)(u >> 16);
}

// ---------- mu stage 1: per-(n,c) sum of y[n][c][:] (1024 blocks, float4) ----------
__global__ void k_mu1(const float* __restrict__ y, float* __restrict__ muP) {
    const int b = blockIdx.x;            // n*128 + c
    const int t = threadIdx.x;
    const float* p = y + (size_t)b * LL;
    float4 v0 = *(const float4*)(p + t * 4);
    float4 v1 = *(const float4*)(p + 1024 + t * 4);
    float4 v2 = *(const float4*)(p + 2048 + t * 4);
    float4 v3 = *(const float4*)(p + 3072 + t * 4);
    float s = (v0.x + v0.y + v0.z + v0.w) + (v1.x + v1.y + v1.z + v1.w)
            + (v2.x + v2.y + v2.z + v2.w) + (v3.x + v3.y + v3.z + v3.w);
    for (int o = 1; o < 64; o <<= 1) s += __shfl_xor(s, o, 64);
    __shared__ float red[4];
    if ((t & 63) == 0) red[t >> 6] = s;
    __syncthreads();
    if (t == 0) muP[b] = (red[0] + red[1]) + (red[2] + red[3]);
}

// ---------- mu stage 2: mu[c] = sum_n muP[n][c] / (NB*LL) ----------
__global__ void k_mu2(const float* __restrict__ muP, float* __restrict__ mu) {
    const int c = threadIdx.x;  // 128
    float s = 0.f;
#pragma unroll
    for (int n = 0; n < NB; ++n) s += muP[n * CC + c];
    mu[c] = s * (1.0f / (float)(NB * LL));
}

// ---------- center, L2-normalize over c, emit bf16 transposed [n][l][c]; x and y in one grid ----------
__global__ __launch_bounds__(256, 2) void k_prep(const float* __restrict__ x, const float* __restrict__ y,
                                                 const float* __restrict__ mu,
                                                 unsigned short* __restrict__ xt, unsigned short* __restrict__ yt) {
    __shared__ float tf[CC][132];  // [c][l] fp32 tile
    __shared__ float ssq[2][CC];
    __shared__ float invn[CC];
    const int b = blockIdx.x;  // 512
    const float* src = (b & 256) ? y : x;
    unsigned short* dst = (b & 256) ? yt : xt;
    const int sub = b & 255;
    const int n = sub >> 5, l0 = (sub & 31) << 7;
    const int t = threadIdx.x;
    const float* g = src + (size_t)n * CL + l0;
#pragma unroll
    for (int it = 0; it < 16; ++it) {
        int id = (it << 8) + t;            // 4096 float4 chunks
        int c = id >> 5, l4 = (id & 31) << 2;
        *(float4*)&tf[c][l4] = *(const float4*)(g + (size_t)c * LL + l4);
    }
    __syncthreads();
    {   // center + sum-of-squares: thread -> (l, c-half)
        const int l = t & 127, half = t >> 7;
        float ss = 0.f;
#pragma unroll
        for (int cc = 0; cc < 64; ++cc) {
            int c = (half << 6) + cc;
            float v = tf[c][l] - mu[c];
            tf[c][l] = v;
            ss += v * v;
        }
        ssq[half][l] = ss;
    }
    __syncthreads();
    if (t < CC) invn[t] = 1.0f / fmaxf(sqrtf(ssq[0][t] + ssq[1][t]), 1e-12f);
    __syncthreads();
    unsigned short* o = dst + ((size_t)n * LL + l0) * CC;
#pragma unroll
    for (int it = 0; it < 8; ++it) {
        int id = (it << 8) + t;            // 2048 chunks of 8 bf16
        int lr = id >> 4, c8 = (id & 15) << 3;
        float w = invn[lr];
        unsigned short h[8] __attribute__((aligned(16)));
#pragma unroll
        for (int j = 0; j < 8; ++j) h[j] = f2bf(tf[c8 + j][lr] * w);
        *(uint4*)&o[(size_t)lr * CC + c8] = *(uint4*)h;
    }
}

// ---------- DMA-stage one 128x128 bf16 tile into unpadded LDS with XOR-granule swizzle ----------
// LDS[r][g] = G[r][g ^ (r&15)]  (granule = 8 bf16 = 16B). Wave w stages rows w*32..w*32+31.
__device__ __forceinline__ void stage_dma(const unsigned short* __restrict__ g,
                                          unsigned short* lds, int t) {
    const int w = t >> 6, ln = t & 63;
#pragma unroll
    for (int c = 0; c < 8; ++c) {
        int rbase = w * 32 + c * 4;
        int row = rbase + (ln >> 4);
        int gg = (ln & 15) ^ (row & 15);
        const unsigned short* gp = g + ((size_t)row << 7) + (gg << 3);
        __builtin_amdgcn_global_load_lds(
            (const __attribute__((address_space(1))) void*)gp,
            (__attribute__((address_space(3))) void*)(lds + (rbase << 7)),
            16, 0, 0);
    }
}

// swizzled fragment read: logical (row r, k-granule kq) -> LDS[r][kq ^ (r&15)]
__device__ __forceinline__ bf16x8 ldsfrag(const unsigned short* lds, int r, int kq) {
    return *(const bf16x8*)&lds[(r << 7) + ((kq ^ (r & 15)) << 3)];
}

// ---------- one-time gather of the fixed tile's fragments from global ----------
__device__ __forceinline__ void gather_frags(const unsigned short* __restrict__ g,  // tile base
                                             bf16x8 (&areg)[4][4], int row0, int lane) {
    const int mr = lane & 15, q = lane >> 4;
    const unsigned short* ab = g + ((size_t)(row0 + mr) << 7) + q * 8;
#pragma unroll
    for (int k0i = 0; k0i < 4; ++k0i)
#pragma unroll
        for (int i = 0; i < 4; ++i)
            areg[k0i][i] = *(const bf16x8*)(ab + ((size_t)(i * 16) << 7) + k0i * 32);
}

// MFMA on one streamed LDS tile: fixed frags in areg, streamed frags read swizzled.
__device__ __forceinline__ void mfma_stream(const bf16x8 (&areg)[4][4], const unsigned short* Bs,
                                            f32x4 (&acc)[4][4], int col0, int lane) {
    const int mr = lane & 15, q = lane >> 4;
#pragma unroll
    for (int k0i = 0; k0i < 4; ++k0i) {
        bf16x8 b[4];
#pragma unroll
        for (int j = 0; j < 4; ++j)
            b[j] = ldsfrag(Bs, col0 + j * 16 + mr, 4 * k0i + q);
#pragma unroll
        for (int i = 0; i < 4; ++i)
#pragma unroll
            for (int j = 0; j < 4; ++j)
                acc[i][j] = __builtin_amdgcn_mfma_f32_16x16x32_bf16(areg[k0i][i], b[j], acc[i][j], 0, 0, 0);
    }
}

// C/D layout (verified R2): value acc[i][j][r] -> row = row0+i*16+q*4+r, col = col0+j*16+(lane&15).

// ---------- pass 1: rowmax partials; fixed A = x-tile (regs), streamed B = y-tiles ----------
__global__ __launch_bounds__(256, 3) void k_rowmax(const unsigned short* __restrict__ xt,
                                                   const unsigned short* __restrict__ yt,
                                                   float* __restrict__ rmP) {
    __shared__ unsigned short Bs[CC * CC];
    const int b = blockIdx.x;  // 1024
    const int n = b >> 7, lt = (b >> 2) & 31, ms = b & 3;
    const int t = threadIdx.x, lane = t & 63, w = t >> 6;
    const int row0 = (w & 1) << 6, col0 = (w >> 1) << 6;
    const int q = lane >> 4;
    bf16x8 areg[4][4];
    gather_frags(xt + ((size_t)(n * LL + lt * 128) << 7), areg, row0, lane);
    float rmax[16];
#pragma unroll
    for (int v = 0; v < 16; ++v) rmax[v] = -1e30f;
    for (int mt = ms * 8; mt < ms * 8 + 8; ++mt) {
        __syncthreads();
        stage_dma(yt + ((size_t)(n * LL + mt * 128) << 7), Bs, t);
        __syncthreads();
        f32x4 acc[4][4];
#pragma unroll
        for (int i = 0; i < 4; ++i)
#pragma unroll
            for (int j = 0; j < 4; ++j) acc[i][j] = 0.f;
        mfma_stream(areg, Bs, acc, col0, lane);
#pragma unroll
        for (int i = 0; i < 4; ++i)
#pragma unroll
            for (int r = 0; r < 4; ++r) {
                float m = acc[i][0][r];
#pragma unroll
                for (int j = 1; j < 4; ++j) m = fmaxf(m, acc[i][j][r]);
                rmax[i * 4 + r] = fmaxf(rmax[i * 4 + r], m);
            }
    }
#pragma unroll
    for (int v = 0; v < 16; ++v) {
        rmax[v] = fmaxf(rmax[v], __shfl_xor(rmax[v], 1, 64));
        rmax[v] = fmaxf(rmax[v], __shfl_xor(rmax[v], 2, 64));
        rmax[v] = fmaxf(rmax[v], __shfl_xor(rmax[v], 4, 64));
        rmax[v] = fmaxf(rmax[v], __shfl_xor(rmax[v], 8, 64));
    }
    if ((lane & 15) == 0) {
        const int part = ms * 2 + (w >> 1);  // 8 disjoint partials
#pragma unroll
        for (int v = 0; v < 16; ++v) {
            int row = lt * 128 + row0 + (v >> 2) * 16 + q * 4 + (v & 3);
            rmP[((size_t)part << 15) + n * LL + row] = rmax[v];
        }
    }
}

// ---------- post1: b2 = beta*log2e only (e2 derived where needed) ----------
__global__ void k_post1(const float* __restrict__ rmP, float* __restrict__ b2A) {
    int i = blockIdx.x * 256 + threadIdx.x;  // 32768
    float rm = -1e30f;
#pragma unroll
    for (int p = 0; p < 8; ++p) rm = fmaxf(rm, rmP[i + ((size_t)p << 15)]);
    float beta = 2.0f / (1.0f - rm + EPSV);
    b2A[i] = beta * L2E;
}

// ---------- pass 2: Z partials = sum_cols 2^(b2*(cos-1) + 2*log2e) ----------
__global__ __launch_bounds__(256, 3) void k_z(const unsigned short* __restrict__ xt,
                                              const unsigned short* __restrict__ yt,
                                              const float* __restrict__ b2A,
                                              float* __restrict__ Zp) {
    __shared__ unsigned short Bs[CC * CC];
    const int b = blockIdx.x;  // 1024
    const int n = b >> 7, lt = (b >> 2) & 31, ms = b & 3;
    const int t = threadIdx.x, lane = t & 63, w = t >> 6;
    const int row0 = (w & 1) << 6, col0 = (w >> 1) << 6;
    const int q = lane >> 4;
    bf16x8 areg[4][4];
    gather_frags(xt + ((size_t)(n * LL + lt * 128) << 7), areg, row0, lane);
    float b2[16], zs[16];
#pragma unroll
    for (int v = 0; v < 16; ++v) {
        int row = lt * 128 + row0 + (v >> 2) * 16 + q * 4 + (v & 3);
        b2[v] = b2A[n * LL + row];
        zs[v] = 0.f;
    }
    for (int mt = ms * 8; mt < ms * 8 + 8; ++mt) {
        __syncthreads();
        stage_dma(yt + ((size_t)(n * LL + mt * 128) << 7), Bs, t);
        __syncthreads();
        f32x4 acc[4][4];
#pragma unroll
        for (int i = 0; i < 4; ++i)
#pragma unroll
            for (int j = 0; j < 4; ++j) acc[i][j] = 0.f;
        mfma_stream(areg, Bs, acc, col0, lane);
#pragma unroll
        for (int i = 0; i < 4; ++i)
#pragma unroll
            for (int r = 0; r < 4; ++r) {
                int v = i * 4 + r;
                float s = 0.f;
#pragma unroll
                for (int j = 0; j < 4; ++j)
                    s += __builtin_amdgcn_exp2f(fmaf(b2[v], acc[i][j][r] - 1.0f, TWO_L2E));
                zs[v] += s;
            }
    }
#pragma unroll
    for (int v = 0; v < 16; ++v) {
        zs[v] += __shfl_xor(zs[v], 1, 64);
        zs[v] += __shfl_xor(zs[v], 2, 64);
        zs[v] += __shfl_xor(zs[v], 4, 64);
        zs[v] += __shfl_xor(zs[v], 8, 64);
    }
    if ((lane & 15) == 0) {
        const int part = ms * 2 + (w >> 1);
#pragma unroll
        for (int v = 0; v < 16; ++v) {
            int row = lt * 128 + row0 + (v >> 2) * 16 + q * 4 + (v & 3);
            Zp[((size_t)part << 15) + n * LL + row] = zs[v];
        }
    }
}

// ---------- post2: g2 = (2*log2e - b2) - log2(Z) ----------
__global__ void k_post2(const float* __restrict__ Zp, const float* __restrict__ b2A,
                        float* __restrict__ g2A) {
    int i = blockIdx.x * 256 + threadIdx.x;
    float Z = 0.f;
#pragma unroll
    for (int p = 0; p < 8; ++p) Z += Zp[i + ((size_t)p << 15)];
    g2A[i] = (TWO_L2E - b2A[i]) - __builtin_amdgcn_logf(Z);
}

// ---------- pass 3: colmax exponent partials; fixed A = y-cols (regs), streamed B = x-tiles ----
__global__ __launch_bounds__(256, 3) void k_colmax(const unsigned short* __restrict__ xt,
                                                   const unsigned short* __restrict__ yt,
                                                   const float* __restrict__ b2A, const float* __restrict__ g2A,
                                                   float* __restrict__ cmP) {
    __shared__ unsigned short Bs[CC * CC];
    const int b = blockIdx.x;  // 1024
    const int n = b >> 7, ct = (b >> 2) & 31, ls = b & 3;
    const int t = threadIdx.x, lane = t & 63, w = t >> 6;
    const int row0 = (w & 1) << 6, col0 = (w >> 1) << 6;
    const int mr = lane & 15, q = lane >> 4;
    bf16x8 areg[4][4];
    gather_frags(yt + ((size_t)(n * LL + ct * 128) << 7), areg, row0, lane);
    float cmax[16];
#pragma unroll
    for (int v = 0; v < 16; ++v) cmax[v] = -1e30f;
    for (int lt = ls * 8; lt < ls * 8 + 8; ++lt) {
        __syncthreads();
        stage_dma(xt + ((size_t)(n * LL + lt * 128) << 7), Bs, t);
        __syncthreads();
        f32x4 acc[4][4];
#pragma unroll
        for (int i = 0; i < 4; ++i)
#pragma unroll
            for (int j = 0; j < 4; ++j) acc[i][j] = 0.f;
        mfma_stream(areg, Bs, acc, col0, lane);
        float b2v[4], g2v[4];
#pragma unroll
        for (int j = 0; j < 4; ++j) {
            int xr = lt * 128 + col0 + j * 16 + mr;
            b2v[j] = b2A[n * LL + xr];
            g2v[j] = g2A[n * LL + xr];
        }
#pragma unroll
        for (int i = 0; i < 4; ++i)
#pragma unroll
            for (int r = 0; r < 4; ++r) {
                int v = i * 4 + r;
                float m = cmax[v];
#pragma unroll
                for (int j = 0; j < 4; ++j)
                    m = fmaxf(m, fmaf(b2v[j], acc[i][j][r], g2v[j]));
                cmax[v] = m;
            }
    }
#pragma unroll
    for (int v = 0; v < 16; ++v) {
        cmax[v] = fmaxf(cmax[v], __shfl_xor(cmax[v], 1, 64));
        cmax[v] = fmaxf(cmax[v], __shfl_xor(cmax[v], 2, 64));
        cmax[v] = fmaxf(cmax[v], __shfl_xor(cmax[v], 4, 64));
        cmax[v] = fmaxf(cmax[v], __shfl_xor(cmax[v], 8, 64));
    }
    if (mr == 0) {
        const int part = ls * 2 + (w >> 1);  // 8 disjoint partials
#pragma unroll
        for (int v = 0; v < 16; ++v) {
            int yc = ct * 128 + row0 + (v >> 2) * 16 + q * 4 + (v & 3);
            cmP[((size_t)part << 15) + n * LL + yc] = cmax[v];
        }
    }
}

// ---------- final loss: colmax = 2^max(partial exponents); loss = mean_n -log(mean + eps) ----------
__global__ void k_loss(const float* __restrict__ cmP, float* __restrict__ out) {
    __shared__ float red[1024];
    const int t = threadIdx.x;
    float loss = 0.f;
    for (int n = 0; n < NB; ++n) {
        float s = 0.f;
        for (int m = t; m < LL; m += 1024) {
            size_t idx = (size_t)n * LL + m;
            float e = -1e30f;
#pragma unroll
            for (int p = 0; p < 8; ++p) e = fmaxf(e, cmP[idx + ((size_t)p << 15)]);
            s += __builtin_amdgcn_exp2f(e);
        }
        red[t] = s;
        __syncthreads();
        for (int o = 512; o > 0; o >>= 1) {
            if (t < o) red[t] += red[t + o];
            __syncthreads();
        }
        if (t == 0) loss += -logf(red[0] * (1.0f / (float)LL) + EPSV);
        __syncthreads();
    }
    if (t == 0) out[0] = loss * (1.0f / (float)NB);
}

extern "C" void kernel_launch(void* const* d_in, const int* in_sizes, int n_in,
                              void* d_out, int out_size, void* d_ws, size_t ws_size,
                              hipStream_t stream) {
    const float* x = (const float*)d_in[0];
    const float* y = (const float*)d_in[1];
    float* out = (float*)d_out;
    char* ws = (char*)d_ws;

    unsigned short* xt = (unsigned short*)ws;                    // 8,388,608 B
    unsigned short* yt = (unsigned short*)(ws + 8388608);        // 8,388,608 B
    char* p = ws + 16777216;
    float* mu  = (float*)p;            p += 512;
    float* muP = (float*)p;            p += 4096;
    float* b2A = (float*)p;            p += 131072;
    float* g2A = (float*)p;            p += 131072;
    float* rmP = (float*)p;            p += 8 * 131072;          // reused as cmP
    float* Zp  = (float*)p;            p += 8 * 131072;          // total ~19.4 MB
    float* cmP = rmP;

    k_mu1<<<1024, 256, 0, stream>>>(y, muP);
    k_mu2<<<1, 128, 0, stream>>>(muP, mu);
    k_prep<<<512, 256, 0, stream>>>(x, y, mu, xt, yt);
    k_rowmax<<<1024, 256, 0, stream>>>(xt, yt, rmP);
    k_post1<<<128, 256, 0, stream>>>(rmP, b2A);
    k_z<<<1024, 256, 0, stream>>>(xt, yt, b2A, Zp);
    k_post2<<<128, 256, 0, stream>>>(Zp, b2A, g2A);
    k_colmax<<<1024, 256, 0, stream>>>(xt, yt, b2A, g2A, cmP);
    k_loss<<<1, 1024, 0, stream>>>(cmP, out);
}

// Round 5
// 220.232 us; speedup vs baseline: 1.3585x; 1.3585x over previous
//
#include <hip/hip_runtime.h>
#include <math.h>

// ContextualLoss 3D: N=8, C=128, L=4096.
// R5: R3 GEMM config restored (256,2; 2-way split; no spills) + LDS double-buffer
//     (DMA next tile during compute, 1 barrier/iter) + fast two-stage k_mu.
// R4 lesson: launch_bounds(256,3) forced 84 VGPR -> 46MB scratch spill traffic. Don't.

#define NB 8
#define CC 128
#define LL 4096
#define CL (CC * LL)
#define EPSV 1e-5f
#define L2E 1.44269504f

typedef __bf16 bf16x8 __attribute__((ext_vector_type(8)));
typedef float f32x4 __attribute__((ext_vector_type(4)));

// f32 -> bf16 bits, round-nearest-even
__device__ __forceinline__ unsigned short f2bf(float f) {
    unsigned u = __float_as_uint(f);
    u += 0x7FFFu + ((u >> 16) & 1u);
    return (unsigned short)(u >> 16);
}

// ---------- mu stage 1: per-(n,c) sum of y[n][c][:] (1024 blocks, float4) ----------
__global__ void k_mu1(const float* __restrict__ y, float* __restrict__ muP) {
    const int b = blockIdx.x;            // n*128 + c
    const int t = threadIdx.x;
    const float* p = y + (size_t)b * LL;
    float4 v0 = *(const float4*)(p + t * 4);
    float4 v1 = *(const float4*)(p + 1024 + t * 4);
    float4 v2 = *(const float4*)(p + 2048 + t * 4);
    float4 v3 = *(const float4*)(p + 3072 + t * 4);
    float s = (v0.x + v0.y + v0.z + v0.w) + (v1.x + v1.y + v1.z + v1.w)
            + (v2.x + v2.y + v2.z + v2.w) + (v3.x + v3.y + v3.z + v3.w);
    for (int o = 1; o < 64; o <<= 1) s += __shfl_xor(s, o, 64);
    __shared__ float red[4];
    if ((t & 63) == 0) red[t >> 6] = s;
    __syncthreads();
    if (t == 0) muP[b] = (red[0] + red[1]) + (red[2] + red[3]);
}

// ---------- mu stage 2: mu[c] = sum_n muP[n][c] / (NB*LL) ----------
__global__ void k_mu2(const float* __restrict__ muP, float* __restrict__ mu) {
    const int c = threadIdx.x;  // 128
    float s = 0.f;
#pragma unroll
    for (int n = 0; n < NB; ++n) s += muP[n * CC + c];
    mu[c] = s * (1.0f / (float)(NB * LL));
}

// ---------- center, L2-normalize over c, emit bf16 transposed [n][l][c]; x and y in one grid ----------
__global__ __launch_bounds__(256, 2) void k_prep(const float* __restrict__ x, const float* __restrict__ y,
                                                 const float* __restrict__ mu,
                                                 unsigned short* __restrict__ xt, unsigned short* __restrict__ yt) {
    __shared__ float tf[CC][132];  // [c][l] fp32 tile
    __shared__ float ssq[2][CC];
    __shared__ float invn[CC];
    const int b = blockIdx.x;  // 512
    const float* src = (b & 256) ? y : x;
    unsigned short* dst = (b & 256) ? yt : xt;
    const int sub = b & 255;
    const int n = sub >> 5, l0 = (sub & 31) << 7;
    const int t = threadIdx.x;
    const float* g = src + (size_t)n * CL + l0;
#pragma unroll
    for (int it = 0; it < 16; ++it) {
        int id = (it << 8) + t;            // 4096 float4 chunks
        int c = id >> 5, l4 = (id & 31) << 2;
        *(float4*)&tf[c][l4] = *(const float4*)(g + (size_t)c * LL + l4);
    }
    __syncthreads();
    {   // center + sum-of-squares: thread -> (l, c-half)
        const int l = t & 127, half = t >> 7;
        float ss = 0.f;
#pragma unroll
        for (int cc = 0; cc < 64; ++cc) {
            int c = (half << 6) + cc;
            float v = tf[c][l] - mu[c];
            tf[c][l] = v;
            ss += v * v;
        }
        ssq[half][l] = ss;
    }
    __syncthreads();
    if (t < CC) invn[t] = 1.0f / fmaxf(sqrtf(ssq[0][t] + ssq[1][t]), 1e-12f);
    __syncthreads();
    unsigned short* o = dst + ((size_t)n * LL + l0) * CC;
#pragma unroll
    for (int it = 0; it < 8; ++it) {
        int id = (it << 8) + t;            // 2048 chunks of 8 bf16
        int lr = id >> 4, c8 = (id & 15) << 3;
        float w = invn[lr];
        unsigned short h[8] __attribute__((aligned(16)));
#pragma unroll
        for (int j = 0; j < 8; ++j) h[j] = f2bf(tf[c8 + j][lr] * w);
        *(uint4*)&o[(size_t)lr * CC + c8] = *(uint4*)h;
    }
}

// ---------- DMA-stage one 128x128 bf16 tile into unpadded LDS with XOR-granule swizzle ----------
// LDS[r][g] = G[r][g ^ (r&15)]  (granule = 8 bf16 = 16B). Wave w stages rows w*32..w*32+31.
__device__ __forceinline__ void stage_dma(const unsigned short* __restrict__ g,
                                          unsigned short* lds, int t) {
    const int w = t >> 6, ln = t & 63;
#pragma unroll
    for (int c = 0; c < 8; ++c) {
        int rbase = w * 32 + c * 4;
        int row = rbase + (ln >> 4);
        int gg = (ln & 15) ^ (row & 15);
        const unsigned short* gp = g + ((size_t)row << 7) + (gg << 3);
        __builtin_amdgcn_global_load_lds(
            (const __attribute__((address_space(1))) void*)gp,
            (__attribute__((address_space(3))) void*)(lds + (rbase << 7)),
            16, 0, 0);
    }
}

// swizzled fragment read: logical (row r, k-granule kq) -> LDS[r][kq ^ (r&15)]
__device__ __forceinline__ bf16x8 ldsfrag(const unsigned short* lds, int r, int kq) {
    return *(const bf16x8*)&lds[(r << 7) + ((kq ^ (r & 15)) << 3)];
}

// ---------- one-time gather of the fixed tile's fragments from global ----------
__device__ __forceinline__ void gather_frags(const unsigned short* __restrict__ g,  // tile base
                                             bf16x8 (&areg)[4][4], int row0, int lane) {
    const int mr = lane & 15, q = lane >> 4;
    const unsigned short* ab = g + ((size_t)(row0 + mr) << 7) + q * 8;
#pragma unroll
    for (int k0i = 0; k0i < 4; ++k0i)
#pragma unroll
        for (int i = 0; i < 4; ++i)
            areg[k0i][i] = *(const bf16x8*)(ab + ((size_t)(i * 16) << 7) + k0i * 32);
}

// MFMA on one streamed LDS tile: fixed frags in areg, streamed frags read swizzled.
__device__ __forceinline__ void mfma_stream(const bf16x8 (&areg)[4][4], const unsigned short* Bs,
                                            f32x4 (&acc)[4][4], int col0, int lane) {
    const int mr = lane & 15, q = lane >> 4;
#pragma unroll
    for (int k0i = 0; k0i < 4; ++k0i) {
        bf16x8 b[4];
#pragma unroll
        for (int j = 0; j < 4; ++j)
            b[j] = ldsfrag(Bs, col0 + j * 16 + mr, 4 * k0i + q);
#pragma unroll
        for (int i = 0; i < 4; ++i)
#pragma unroll
            for (int j = 0; j < 4; ++j)
                acc[i][j] = __builtin_amdgcn_mfma_f32_16x16x32_bf16(areg[k0i][i], b[j], acc[i][j], 0, 0, 0);
    }
}

// C/D layout (verified R2): value acc[i][j][r] -> row = row0+i*16+q*4+r, col = col0+j*16+(lane&15).

// ---------- pass 1: rowmax partials; fixed A = x-tile (regs), streamed dbuf B = y-tiles ----------
__global__ __launch_bounds__(256, 2) void k_rowmax(const unsigned short* __restrict__ xt,
                                                   const unsigned short* __restrict__ yt,
                                                   float* __restrict__ rmP) {
    __shared__ unsigned short Bs[2][CC * CC];
    const int b = blockIdx.x;  // 512
    const int n = b >> 6, lt = (b >> 1) & 31, ms = b & 1;
    const int t = threadIdx.x, lane = t & 63, w = t >> 6;
    const int row0 = (w & 1) << 6, col0 = (w >> 1) << 6;
    const int q = lane >> 4;
    const unsigned short* ytn = yt + ((size_t)n * LL << 7);
    bf16x8 areg[4][4];
    gather_frags(xt + ((size_t)(n * LL + lt * 128) << 7), areg, row0, lane);
    float rmax[16];
#pragma unroll
    for (int v = 0; v < 16; ++v) rmax[v] = -1e30f;
    stage_dma(ytn + ((size_t)(ms * 16 * 128) << 7), Bs[0], t);
    __syncthreads();
    int pb = 0;
    for (int mt = ms * 16; mt < ms * 16 + 16; ++mt) {
        if (mt + 1 < ms * 16 + 16)
            stage_dma(ytn + ((size_t)((mt + 1) * 128) << 7), Bs[pb ^ 1], t);
        f32x4 acc[4][4];
#pragma unroll
        for (int i = 0; i < 4; ++i)
#pragma unroll
            for (int j = 0; j < 4; ++j) acc[i][j] = 0.f;
        mfma_stream(areg, Bs[pb], acc, col0, lane);
#pragma unroll
        for (int i = 0; i < 4; ++i)
#pragma unroll
            for (int r = 0; r < 4; ++r) {
                float m = acc[i][0][r];
#pragma unroll
                for (int j = 1; j < 4; ++j) m = fmaxf(m, acc[i][j][r]);
                rmax[i * 4 + r] = fmaxf(rmax[i * 4 + r], m);
            }
        __syncthreads();
        pb ^= 1;
    }
#pragma unroll
    for (int v = 0; v < 16; ++v) {
        rmax[v] = fmaxf(rmax[v], __shfl_xor(rmax[v], 1, 64));
        rmax[v] = fmaxf(rmax[v], __shfl_xor(rmax[v], 2, 64));
        rmax[v] = fmaxf(rmax[v], __shfl_xor(rmax[v], 4, 64));
        rmax[v] = fmaxf(rmax[v], __shfl_xor(rmax[v], 8, 64));
    }
    if ((lane & 15) == 0) {
        const int part = ms * 2 + (w >> 1);  // 4 disjoint partials
#pragma unroll
        for (int v = 0; v < 16; ++v) {
            int row = lt * 128 + row0 + (v >> 2) * 16 + q * 4 + (v & 3);
            rmP[((size_t)part << 15) + n * LL + row] = rmax[v];
        }
    }
}

// ---------- post1: b2 = beta*log2e, e2 = (2-beta)*log2e ----------
__global__ void k_post1(const float* __restrict__ rmP, float* __restrict__ b2A, float* __restrict__ e2A) {
    int i = blockIdx.x * 256 + threadIdx.x;  // 32768
    float rm = fmaxf(fmaxf(rmP[i], rmP[i + (1 << 15)]),
                     fmaxf(rmP[i + (2 << 15)], rmP[i + (3 << 15)]));
    float beta = 2.0f / (1.0f - rm + EPSV);
    b2A[i] = beta * L2E;
    e2A[i] = (2.0f - beta) * L2E;
}

// ---------- pass 2: Z partials = sum_cols 2^(b2*cos + e2) ----------
__global__ __launch_bounds__(256, 2) void k_z(const unsigned short* __restrict__ xt,
                                              const unsigned short* __restrict__ yt,
                                              const float* __restrict__ b2A, const float* __restrict__ e2A,
                                              float* __restrict__ Zp) {
    __shared__ unsigned short Bs[2][CC * CC];
    const int b = blockIdx.x;  // 512
    const int n = b >> 6, lt = (b >> 1) & 31, ms = b & 1;
    const int t = threadIdx.x, lane = t & 63, w = t >> 6;
    const int row0 = (w & 1) << 6, col0 = (w >> 1) << 6;
    const int q = lane >> 4;
    const unsigned short* ytn = yt + ((size_t)n * LL << 7);
    bf16x8 areg[4][4];
    gather_frags(xt + ((size_t)(n * LL + lt * 128) << 7), areg, row0, lane);
    float b2[16], e2[16], zs[16];
#pragma unroll
    for (int v = 0; v < 16; ++v) {
        int row = lt * 128 + row0 + (v >> 2) * 16 + q * 4 + (v & 3);
        b2[v] = b2A[n * LL + row];
        e2[v] = e2A[n * LL + row];
        zs[v] = 0.f;
    }
    stage_dma(ytn + ((size_t)(ms * 16 * 128) << 7), Bs[0], t);
    __syncthreads();
    int pb = 0;
    for (int mt = ms * 16; mt < ms * 16 + 16; ++mt) {
        if (mt + 1 < ms * 16 + 16)
            stage_dma(ytn + ((size_t)((mt + 1) * 128) << 7), Bs[pb ^ 1], t);
        f32x4 acc[4][4];
#pragma unroll
        for (int i = 0; i < 4; ++i)
#pragma unroll
            for (int j = 0; j < 4; ++j) acc[i][j] = 0.f;
        mfma_stream(areg, Bs[pb], acc, col0, lane);
#pragma unroll
        for (int i = 0; i < 4; ++i)
#pragma unroll
            for (int r = 0; r < 4; ++r) {
                int v = i * 4 + r;
                float s = 0.f;
#pragma unroll
                for (int j = 0; j < 4; ++j)
                    s += __builtin_amdgcn_exp2f(fmaf(b2[v], acc[i][j][r], e2[v]));
                zs[v] += s;
            }
        __syncthreads();
        pb ^= 1;
    }
#pragma unroll
    for (int v = 0; v < 16; ++v) {
        zs[v] += __shfl_xor(zs[v], 1, 64);
        zs[v] += __shfl_xor(zs[v], 2, 64);
        zs[v] += __shfl_xor(zs[v], 4, 64);
        zs[v] += __shfl_xor(zs[v], 8, 64);
    }
    if ((lane & 15) == 0) {
        const int part = ms * 2 + (w >> 1);
#pragma unroll
        for (int v = 0; v < 16; ++v) {
            int row = lt * 128 + row0 + (v >> 2) * 16 + q * 4 + (v & 3);
            Zp[((size_t)part << 15) + n * LL + row] = zs[v];
        }
    }
}

// ---------- post2: g2 = e2 - log2(Z) ----------
__global__ void k_post2(const float* __restrict__ Zp, const float* __restrict__ e2A,
                        float* __restrict__ g2A) {
    int i = blockIdx.x * 256 + threadIdx.x;
    float Z = (Zp[i] + Zp[i + (1 << 15)]) + (Zp[i + (2 << 15)] + Zp[i + (3 << 15)]);
    g2A[i] = e2A[i] - __builtin_amdgcn_logf(Z);
}

// ---------- pass 3: colmax exponent partials; fixed A = y-cols (regs), streamed dbuf B = x-tiles ----
__global__ __launch_bounds__(256, 2) void k_colmax(const unsigned short* __restrict__ xt,
                                                   const unsigned short* __restrict__ yt,
                                                   const float* __restrict__ b2A, const float* __restrict__ g2A,
                                                   float* __restrict__ cmP) {
    __shared__ unsigned short Bs[2][CC * CC];
    const int b = blockIdx.x;  // 512
    const int n = b >> 6, ct = (b >> 1) & 31, ls = b & 1;
    const int t = threadIdx.x, lane = t & 63, w = t >> 6;
    const int row0 = (w & 1) << 6, col0 = (w >> 1) << 6;
    const int mr = lane & 15, q = lane >> 4;
    const unsigned short* xtn = xt + ((size_t)n * LL << 7);
    bf16x8 areg[4][4];
    gather_frags(yt + ((size_t)(n * LL + ct * 128) << 7), areg, row0, lane);
    float cmax[16];
#pragma unroll
    for (int v = 0; v < 16; ++v) cmax[v] = -1e30f;
    stage_dma(xtn + ((size_t)(ls * 16 * 128) << 7), Bs[0], t);
    __syncthreads();
    int pb = 0;
    for (int lt = ls * 16; lt < ls * 16 + 16; ++lt) {
        if (lt + 1 < ls * 16 + 16)
            stage_dma(xtn + ((size_t)((lt + 1) * 128) << 7), Bs[pb ^ 1], t);
        f32x4 acc[4][4];
#pragma unroll
        for (int i = 0; i < 4; ++i)
#pragma unroll
            for (int j = 0; j < 4; ++j) acc[i][j] = 0.f;
        mfma_stream(areg, Bs[pb], acc, col0, lane);
        float b2v[4], g2v[4];
#pragma unroll
        for (int j = 0; j < 4; ++j) {
            int xr = lt * 128 + col0 + j * 16 + mr;
            b2v[j] = b2A[n * LL + xr];
            g2v[j] = g2A[n * LL + xr];
        }
#pragma unroll
        for (int i = 0; i < 4; ++i)
#pragma unroll
            for (int r = 0; r < 4; ++r) {
                int v = i * 4 + r;
                float m = cmax[v];
#pragma unroll
                for (int j = 0; j < 4; ++j)
                    m = fmaxf(m, fmaf(b2v[j], acc[i][j][r], g2v[j]));
                cmax[v] = m;
            }
        __syncthreads();
        pb ^= 1;
    }
#pragma unroll
    for (int v = 0; v < 16; ++v) {
        cmax[v] = fmaxf(cmax[v], __shfl_xor(cmax[v], 1, 64));
        cmax[v] = fmaxf(cmax[v], __shfl_xor(cmax[v], 2, 64));
        cmax[v] = fmaxf(cmax[v], __shfl_xor(cmax[v], 4, 64));
        cmax[v] = fmaxf(cmax[v], __shfl_xor(cmax[v], 8, 64));
    }
    if (mr == 0) {
        const int part = ls * 2 + (w >> 1);  // 4 disjoint partials
#pragma unroll
        for (int v = 0; v < 16; ++v) {
            int yc = ct * 128 + row0 + (v >> 2) * 16 + q * 4 + (v & 3);
            cmP[((size_t)part << 15) + n * LL + yc] = cmax[v];
        }
    }
}

// ---------- final loss: colmax = 2^max(partial exponents); loss = mean_n -log(mean + eps) ----------
__global__ void k_loss(const float* __restrict__ cmP, float* __restrict__ out) {
    __shared__ float red[1024];
    const int t = threadIdx.x;
    float loss = 0.f;
    for (int n = 0; n < NB; ++n) {
        float s = 0.f;
        for (int m = t; m < LL; m += 1024) {
            size_t idx = (size_t)n * LL + m;
            float e = fmaxf(fmaxf(cmP[idx], cmP[idx + (1 << 15)]),
                            fmaxf(cmP[idx + (2 << 15)], cmP[idx + (3 << 15)]));
            s += __builtin_amdgcn_exp2f(e);
        }
        red[t] = s;
        __syncthreads();
        for (int o = 512; o > 0; o >>= 1) {
            if (t < o) red[t] += red[t + o];
            __syncthreads();
        }
        if (t == 0) loss += -logf(red[0] * (1.0f / (float)LL) + EPSV);
        __syncthreads();
    }
    if (t == 0) out[0] = loss * (1.0f / (float)NB);
}

extern "C" void kernel_launch(void* const* d_in, const int* in_sizes, int n_in,
                              void* d_out, int out_size, void* d_ws, size_t ws_size,
                              hipStream_t stream) {
    const float* x = (const float*)d_in[0];
    const float* y = (const float*)d_in[1];
    float* out = (float*)d_out;
    char* ws = (char*)d_ws;

    unsigned short* xt = (unsigned short*)ws;                    // 8,388,608 B
    unsigned short* yt = (unsigned short*)(ws + 8388608);        // 8,388,608 B
    char* p = ws + 16777216;
    float* mu  = (float*)p;            p += 512;
    float* muP = (float*)p;            p += 4096;
    float* b2A = (float*)p;            p += 131072;
    float* e2A = (float*)p;            p += 131072;
    float* g2A = (float*)p;            p += 131072;
    float* rmP = (float*)p;            p += 4 * 131072;          // reused as cmP
    float* Zp  = (float*)p;            p += 4 * 131072;          // total ~19 MB
    float* cmP = rmP;

    k_mu1<<<1024, 256, 0, stream>>>(y, muP);
    k_mu2<<<1, 128, 0, stream>>>(muP, mu);
    k_prep<<<512, 256, 0, stream>>>(x, y, mu, xt, yt);
    k_rowmax<<<512, 256, 0, stream>>>(xt, yt, rmP);
    k_post1<<<128, 256, 0, stream>>>(rmP, b2A, e2A);
    k_z<<<512, 256, 0, stream>>>(xt, yt, b2A, e2A, Zp);
    k_post2<<<128, 256, 0, stream>>>(Zp, e2A, g2A);
    k_colmax<<<512, 256, 0, stream>>>(xt, yt, b2A, g2A, cmP);
    k_loss<<<1, 1024, 0, stream>>>(cmP, out);
}

// Round 6
// 209.510 us; speedup vs baseline: 1.4280x; 1.0512x over previous
//
#include <hip/hip_runtime.h>
#include <math.h>

// ContextualLoss 3D: N=8, C=128, L=4096.
// R6: R3 single-buffer GEMM body (120 VGPR, no spill) + grid 1024 (4-way stream split)
//     for 4 blocks/CU => 4 waves/SIMD, XCD-grouped decode (same-stream blocks share an XCD L2),
//     8-block k_loss with atomicAdd.
// R4 lesson: never cap VGPR via launch_bounds (84 regs -> 46MB scratch). Occupancy comes
// from more *blocks* at 32KB LDS, natural register allocation.

#define NB 8
#define CC 128
#define LL 4096
#define CL (CC * LL)
#define EPSV 1e-5f
#define L2E 1.44269504f

typedef __bf16 bf16x8 __attribute__((ext_vector_type(8)));
typedef float f32x4 __attribute__((ext_vector_type(4)));

// f32 -> bf16 bits, round-nearest-even
__device__ __forceinline__ unsigned short f2bf(float f) {
    unsigned u = __float_as_uint(f);
    u += 0x7FFFu + ((u >> 16) & 1u);
    return (unsigned short)(u >> 16);
}

// ---------- mu stage 1: per-(n,c) sum of y[n][c][:] (1024 blocks, float4) ----------
__global__ void k_mu1(const float* __restrict__ y, float* __restrict__ muP) {
    const int b = blockIdx.x;            // n*128 + c
    const int t = threadIdx.x;
    const float* p = y + (size_t)b * LL;
    float4 v0 = *(const float4*)(p + t * 4);
    float4 v1 = *(const float4*)(p + 1024 + t * 4);
    float4 v2 = *(const float4*)(p + 2048 + t * 4);
    float4 v3 = *(const float4*)(p + 3072 + t * 4);
    float s = (v0.x + v0.y + v0.z + v0.w) + (v1.x + v1.y + v1.z + v1.w)
            + (v2.x + v2.y + v2.z + v2.w) + (v3.x + v3.y + v3.z + v3.w);
    for (int o = 1; o < 64; o <<= 1) s += __shfl_xor(s, o, 64);
    __shared__ float red[4];
    if ((t & 63) == 0) red[t >> 6] = s;
    __syncthreads();
    if (t == 0) muP[b] = (red[0] + red[1]) + (red[2] + red[3]);
}

// ---------- mu stage 2: mu[c] = sum_n muP[n][c] / (NB*LL); also zero the loss accumulator ----------
__global__ void k_mu2(const float* __restrict__ muP, float* __restrict__ mu, float* __restrict__ out) {
    const int c = threadIdx.x;  // 128
    float s = 0.f;
#pragma unroll
    for (int n = 0; n < NB; ++n) s += muP[n * CC + c];
    mu[c] = s * (1.0f / (float)(NB * LL));
    if (c == 0) out[0] = 0.f;   // k_loss atomicAdds into this (stream-ordered after us)
}

// ---------- center, L2-normalize over c, emit bf16 transposed [n][l][c]; x and y in one grid ----------
__global__ __launch_bounds__(256, 2) void k_prep(const float* __restrict__ x, const float* __restrict__ y,
                                                 const float* __restrict__ mu,
                                                 unsigned short* __restrict__ xt, unsigned short* __restrict__ yt) {
    __shared__ float tf[CC][132];  // [c][l] fp32 tile
    __shared__ float ssq[2][CC];
    __shared__ float invn[CC];
    const int b = blockIdx.x;  // 512
    const float* src = (b & 256) ? y : x;
    unsigned short* dst = (b & 256) ? yt : xt;
    const int sub = b & 255;
    const int n = sub >> 5, l0 = (sub & 31) << 7;
    const int t = threadIdx.x;
    const float* g = src + (size_t)n * CL + l0;
#pragma unroll
    for (int it = 0; it < 16; ++it) {
        int id = (it << 8) + t;            // 4096 float4 chunks
        int c = id >> 5, l4 = (id & 31) << 2;
        *(float4*)&tf[c][l4] = *(const float4*)(g + (size_t)c * LL + l4);
    }
    __syncthreads();
    {   // center + sum-of-squares: thread -> (l, c-half)
        const int l = t & 127, half = t >> 7;
        float ss = 0.f;
#pragma unroll
        for (int cc = 0; cc < 64; ++cc) {
            int c = (half << 6) + cc;
            float v = tf[c][l] - mu[c];
            tf[c][l] = v;
            ss += v * v;
        }
        ssq[half][l] = ss;
    }
    __syncthreads();
    if (t < CC) invn[t] = 1.0f / fmaxf(sqrtf(ssq[0][t] + ssq[1][t]), 1e-12f);
    __syncthreads();
    unsigned short* o = dst + ((size_t)n * LL + l0) * CC;
#pragma unroll
    for (int it = 0; it < 8; ++it) {
        int id = (it << 8) + t;            // 2048 chunks of 8 bf16
        int lr = id >> 4, c8 = (id & 15) << 3;
        float w = invn[lr];
        unsigned short h[8] __attribute__((aligned(16)));
#pragma unroll
        for (int j = 0; j < 8; ++j) h[j] = f2bf(tf[c8 + j][lr] * w);
        *(uint4*)&o[(size_t)lr * CC + c8] = *(uint4*)h;
    }
}

// ---------- DMA-stage one 128x128 bf16 tile into unpadded LDS with XOR-granule swizzle ----------
// LDS[r][g] = G[r][g ^ (r&15)]  (granule = 8 bf16 = 16B). Wave w stages rows w*32..w*32+31.
__device__ __forceinline__ void stage_dma(const unsigned short* __restrict__ g,
                                          unsigned short* lds, int t) {
    const int w = t >> 6, ln = t & 63;
#pragma unroll
    for (int c = 0; c < 8; ++c) {
        int rbase = w * 32 + c * 4;
        int row = rbase + (ln >> 4);
        int gg = (ln & 15) ^ (row & 15);
        const unsigned short* gp = g + ((size_t)row << 7) + (gg << 3);
        __builtin_amdgcn_global_load_lds(
            (const __attribute__((address_space(1))) void*)gp,
            (__attribute__((address_space(3))) void*)(lds + (rbase << 7)),
            16, 0, 0);
    }
}

// swizzled fragment read: logical (row r, k-granule kq) -> LDS[r][kq ^ (r&15)]
__device__ __forceinline__ bf16x8 ldsfrag(const unsigned short* lds, int r, int kq) {
    return *(const bf16x8*)&lds[(r << 7) + ((kq ^ (r & 15)) << 3)];
}

// ---------- one-time gather of the fixed tile's fragments from global ----------
__device__ __forceinline__ void gather_frags(const unsigned short* __restrict__ g,  // tile base
                                             bf16x8 (&areg)[4][4], int row0, int lane) {
    const int mr = lane & 15, q = lane >> 4;
    const unsigned short* ab = g + ((size_t)(row0 + mr) << 7) + q * 8;
#pragma unroll
    for (int k0i = 0; k0i < 4; ++k0i)
#pragma unroll
        for (int i = 0; i < 4; ++i)
            areg[k0i][i] = *(const bf16x8*)(ab + ((size_t)(i * 16) << 7) + k0i * 32);
}

// MFMA on one streamed LDS tile: fixed frags in areg, streamed frags read swizzled.
__device__ __forceinline__ void mfma_stream(const bf16x8 (&areg)[4][4], const unsigned short* Bs,
                                            f32x4 (&acc)[4][4], int col0, int lane) {
    const int mr = lane & 15, q = lane >> 4;
#pragma unroll
    for (int k0i = 0; k0i < 4; ++k0i) {
        bf16x8 b[4];
#pragma unroll
        for (int j = 0; j < 4; ++j)
            b[j] = ldsfrag(Bs, col0 + j * 16 + mr, 4 * k0i + q);
#pragma unroll
        for (int i = 0; i < 4; ++i)
#pragma unroll
            for (int j = 0; j < 4; ++j)
                acc[i][j] = __builtin_amdgcn_mfma_f32_16x16x32_bf16(areg[k0i][i], b[j], acc[i][j], 0, 0, 0);
    }
}

// C/D layout (verified R2): value acc[i][j][r] -> row = row0+i*16+q*4+r, col = col0+j*16+(lane&15).

// XCD-grouped decode for grid 1024: the 32 blocks sharing one (n, split) stream all get
// the same (b&7) => same XCD (round-robin dispatch), so the 256KB stream stays in that L2.
#define DECODE_B(b, n_, lt_, ms_)                          \
    const int xcd_ = (b) & 7, slot_ = (b) >> 3;            \
    const int grp_ = xcd_ * 4 + (slot_ >> 5);              \
    const int n_ = grp_ >> 2, ms_ = grp_ & 3, lt_ = slot_ & 31;

// ---------- pass 1: rowmax partials; fixed A = x-tile (regs), streamed B = y-tiles ----------
__global__ __launch_bounds__(256, 2) void k_rowmax(const unsigned short* __restrict__ xt,
                                                   const unsigned short* __restrict__ yt,
                                                   float* __restrict__ rmP) {
    __shared__ unsigned short Bs[CC * CC];
    DECODE_B(blockIdx.x, n, lt, ms)
    const int t = threadIdx.x, lane = t & 63, w = t >> 6;
    const int row0 = (w & 1) << 6, col0 = (w >> 1) << 6;
    const int q = lane >> 4;
    bf16x8 areg[4][4];
    gather_frags(xt + ((size_t)(n * LL + lt * 128) << 7), areg, row0, lane);
    float rmax[16];
#pragma unroll
    for (int v = 0; v < 16; ++v) rmax[v] = -1e30f;
    for (int mt = ms * 8; mt < ms * 8 + 8; ++mt) {
        __syncthreads();
        stage_dma(yt + ((size_t)(n * LL + mt * 128) << 7), Bs, t);
        __syncthreads();
        f32x4 acc[4][4];
#pragma unroll
        for (int i = 0; i < 4; ++i)
#pragma unroll
            for (int j = 0; j < 4; ++j) acc[i][j] = 0.f;
        mfma_stream(areg, Bs, acc, col0, lane);
#pragma unroll
        for (int i = 0; i < 4; ++i)
#pragma unroll
            for (int r = 0; r < 4; ++r) {
                float m = acc[i][0][r];
#pragma unroll
                for (int j = 1; j < 4; ++j) m = fmaxf(m, acc[i][j][r]);
                rmax[i * 4 + r] = fmaxf(rmax[i * 4 + r], m);
            }
    }
#pragma unroll
    for (int v = 0; v < 16; ++v) {
        rmax[v] = fmaxf(rmax[v], __shfl_xor(rmax[v], 1, 64));
        rmax[v] = fmaxf(rmax[v], __shfl_xor(rmax[v], 2, 64));
        rmax[v] = fmaxf(rmax[v], __shfl_xor(rmax[v], 4, 64));
        rmax[v] = fmaxf(rmax[v], __shfl_xor(rmax[v], 8, 64));
    }
    if ((lane & 15) == 0) {
        const int part = ms * 2 + (w >> 1);  // 8 disjoint partials
#pragma unroll
        for (int v = 0; v < 16; ++v) {
            int row = lt * 128 + row0 + (v >> 2) * 16 + q * 4 + (v & 3);
            rmP[((size_t)part << 15) + n * LL + row] = rmax[v];
        }
    }
}

// ---------- post1: b2 = beta*log2e, e2 = (2-beta)*log2e ----------
__global__ void k_post1(const float* __restrict__ rmP, float* __restrict__ b2A, float* __restrict__ e2A) {
    int i = blockIdx.x * 256 + threadIdx.x;  // 32768
    float rm = -1e30f;
#pragma unroll
    for (int p = 0; p < 8; ++p) rm = fmaxf(rm, rmP[i + ((size_t)p << 15)]);
    float beta = 2.0f / (1.0f - rm + EPSV);
    b2A[i] = beta * L2E;
    e2A[i] = (2.0f - beta) * L2E;
}

// ---------- pass 2: Z partials = sum_cols 2^(b2*cos + e2) ----------
__global__ __launch_bounds__(256, 2) void k_z(const unsigned short* __restrict__ xt,
                                              const unsigned short* __restrict__ yt,
                                              const float* __restrict__ b2A, const float* __restrict__ e2A,
                                              float* __restrict__ Zp) {
    __shared__ unsigned short Bs[CC * CC];
    DECODE_B(blockIdx.x, n, lt, ms)
    const int t = threadIdx.x, lane = t & 63, w = t >> 6;
    const int row0 = (w & 1) << 6, col0 = (w >> 1) << 6;
    const int q = lane >> 4;
    bf16x8 areg[4][4];
    gather_frags(xt + ((size_t)(n * LL + lt * 128) << 7), areg, row0, lane);
    float b2[16], e2[16], zs[16];
#pragma unroll
    for (int v = 0; v < 16; ++v) {
        int row = lt * 128 + row0 + (v >> 2) * 16 + q * 4 + (v & 3);
        b2[v] = b2A[n * LL + row];
        e2[v] = e2A[n * LL + row];
        zs[v] = 0.f;
    }
    for (int mt = ms * 8; mt < ms * 8 + 8; ++mt) {
        __syncthreads();
        stage_dma(yt + ((size_t)(n * LL + mt * 128) << 7), Bs, t);
        __syncthreads();
        f32x4 acc[4][4];
#pragma unroll
        for (int i = 0; i < 4; ++i)
#pragma unroll
            for (int j = 0; j < 4; ++j) acc[i][j] = 0.f;
        mfma_stream(areg, Bs, acc, col0, lane);
#pragma unroll
        for (int i = 0; i < 4; ++i)
#pragma unroll
            for (int r = 0; r < 4; ++r) {
                int v = i * 4 + r;
                float s = 0.f;
#pragma unroll
                for (int j = 0; j < 4; ++j)
                    s += __builtin_amdgcn_exp2f(fmaf(b2[v], acc[i][j][r], e2[v]));
                zs[v] += s;
            }
    }
#pragma unroll
    for (int v = 0; v < 16; ++v) {
        zs[v] += __shfl_xor(zs[v], 1, 64);
        zs[v] += __shfl_xor(zs[v], 2, 64);
        zs[v] += __shfl_xor(zs[v], 4, 64);
        zs[v] += __shfl_xor(zs[v], 8, 64);
    }
    if ((lane & 15) == 0) {
        const int part = ms * 2 + (w >> 1);
#pragma unroll
        for (int v = 0; v < 16; ++v) {
            int row = lt * 128 + row0 + (v >> 2) * 16 + q * 4 + (v & 3);
            Zp[((size_t)part << 15) + n * LL + row] = zs[v];
        }
    }
}

// ---------- post2: g2 = e2 - log2(Z) ----------
__global__ void k_post2(const float* __restrict__ Zp, const float* __restrict__ e2A,
                        float* __restrict__ g2A) {
    int i = blockIdx.x * 256 + threadIdx.x;
    float Z = 0.f;
#pragma unroll
    for (int p = 0; p < 8; ++p) Z += Zp[i + ((size_t)p << 15)];
    g2A[i] = e2A[i] - __builtin_amdgcn_logf(Z);
}

// ---------- pass 3: colmax exponent partials; fixed A = y-cols (regs), streamed B = x-tiles ----
__global__ __launch_bounds__(256, 2) void k_colmax(const unsigned short* __restrict__ xt,
                                                   const unsigned short* __restrict__ yt,
                                                   const float* __restrict__ b2A, const float* __restrict__ g2A,
                                                   float* __restrict__ cmP) {
    __shared__ unsigned short Bs[CC * CC];
    DECODE_B(blockIdx.x, n, ct, ls)
    const int t = threadIdx.x, lane = t & 63, w = t >> 6;
    const int row0 = (w & 1) << 6, col0 = (w >> 1) << 6;
    const int mr = lane & 15, q = lane >> 4;
    bf16x8 areg[4][4];
    gather_frags(yt + ((size_t)(n * LL + ct * 128) << 7), areg, row0, lane);
    float cmax[16];
#pragma unroll
    for (int v = 0; v < 16; ++v) cmax[v] = -1e30f;
    for (int lt = ls * 8; lt < ls * 8 + 8; ++lt) {
        __syncthreads();
        stage_dma(xt + ((size_t)(n * LL + lt * 128) << 7), Bs, t);
        __syncthreads();
        f32x4 acc[4][4];
#pragma unroll
        for (int i = 0; i < 4; ++i)
#pragma unroll
            for (int j = 0; j < 4; ++j) acc[i][j] = 0.f;
        mfma_stream(areg, Bs, acc, col0, lane);
        float b2v[4], g2v[4];
#pragma unroll
        for (int j = 0; j < 4; ++j) {
            int xr = lt * 128 + col0 + j * 16 + mr;
            b2v[j] = b2A[n * LL + xr];
            g2v[j] = g2A[n * LL + xr];
        }
#pragma unroll
        for (int i = 0; i < 4; ++i)
#pragma unroll
            for (int r = 0; r < 4; ++r) {
                int v = i * 4 + r;
                float m = cmax[v];
#pragma unroll
                for (int j = 0; j < 4; ++j)
                    m = fmaxf(m, fmaf(b2v[j], acc[i][j][r], g2v[j]));
                cmax[v] = m;
            }
    }
#pragma unroll
    for (int v = 0; v < 16; ++v) {
        cmax[v] = fmaxf(cmax[v], __shfl_xor(cmax[v], 1, 64));
        cmax[v] = fmaxf(cmax[v], __shfl_xor(cmax[v], 2, 64));
        cmax[v] = fmaxf(cmax[v], __shfl_xor(cmax[v], 4, 64));
        cmax[v] = fmaxf(cmax[v], __shfl_xor(cmax[v], 8, 64));
    }
    if (mr == 0) {
        const int part = ls * 2 + (w >> 1);  // 8 disjoint partials
#pragma unroll
        for (int v = 0; v < 16; ++v) {
            int yc = ct * 128 + row0 + (v >> 2) * 16 + q * 4 + (v & 3);
            cmP[((size_t)part << 15) + n * LL + yc] = cmax[v];
        }
    }
}

// ---------- final loss: 8 blocks (one per n), atomicAdd the per-n term ----------
__global__ void k_loss(const float* __restrict__ cmP, float* __restrict__ out) {
    __shared__ float red[256];
    const int n = blockIdx.x, t = threadIdx.x;
    float s = 0.f;
    for (int m = t; m < LL; m += 256) {
        size_t idx = (size_t)n * LL + m;
        float e = -1e30f;
#pragma unroll
        for (int p = 0; p < 8; ++p) e = fmaxf(e, cmP[idx + ((size_t)p << 15)]);
        s += __builtin_amdgcn_exp2f(e);
    }
    red[t] = s;
    __syncthreads();
    for (int o = 128; o > 0; o >>= 1) {
        if (t < o) red[t] += red[t + o];
        __syncthreads();
    }
    if (t == 0)
        atomicAdd(out, -logf(red[0] * (1.0f / (float)LL) + EPSV) * (1.0f / (float)NB));
}

extern "C" void kernel_launch(void* const* d_in, const int* in_sizes, int n_in,
                              void* d_out, int out_size, void* d_ws, size_t ws_size,
                              hipStream_t stream) {
    const float* x = (const float*)d_in[0];
    const float* y = (const float*)d_in[1];
    float* out = (float*)d_out;
    char* ws = (char*)d_ws;

    unsigned short* xt = (unsigned short*)ws;                    // 8,388,608 B
    unsigned short* yt = (unsigned short*)(ws + 8388608);        // 8,388,608 B
    char* p = ws + 16777216;
    float* mu  = (float*)p;            p += 512;
    float* muP = (float*)p;            p += 4096;
    float* b2A = (float*)p;            p += 131072;
    float* e2A = (float*)p;            p += 131072;
    float* g2A = (float*)p;            p += 131072;
    float* rmP = (float*)p;            p += 8 * 131072;          // reused as cmP
    float* Zp  = (float*)p;            p += 8 * 131072;          // total ~19.3 MB
    float* cmP = rmP;

    k_mu1<<<1024, 256, 0, stream>>>(y, muP);
    k_mu2<<<1, 128, 0, stream>>>(muP, mu, out);
    k_prep<<<512, 256, 0, stream>>>(x, y, mu, xt, yt);
    k_rowmax<<<1024, 256, 0, stream>>>(xt, yt, rmP);
    k_post1<<<128, 256, 0, stream>>>(rmP, b2A, e2A);
    k_z<<<1024, 256, 0, stream>>>(xt, yt, b2A, e2A, Zp);
    k_post2<<<128, 256, 0, stream>>>(Zp, e2A, g2A);
    k_colmax<<<1024, 256, 0, stream>>>(xt, yt, b2A, g2A, cmP);
    k_loss<<<8, 256, 0, stream>>>(cmP, out);
}